// Round 8
// baseline (629.298 us; speedup 1.0000x reference)
//
#include <hip/hip_runtime.h>

// Problem constants (match reference)
#define NN   100000              // nodes
#define NE   1600000             // edges before self loops
#define ET   (NE + NN)           // edges incl. self loops
#define INF_ 128                 // input features
#define HID  64                  // hidden
#define NG   256                 // graphs
#define BN_EPS 1e-5f
#define NEG  0.2f

// hierarchical scan geometry
#define SCAN_T     256
#define SCAN_ELEM  8
#define SCAN_CHUNK (SCAN_T * SCAN_ELEM)
#define SCAN_NB    ((NN + SCAN_CHUNK - 1) / SCAN_CHUNK)  // 49 (<= 64, fits a wave)

// bucket partition geometry (CSR fill)
#define BSPAN_LOG 8
#define BSPAN     (1 << BSPAN_LOG)                 // 256 dst nodes per bucket
#define NBUK      ((NN + BSPAN - 1) / BSPAN)       // 391
#define P1_EPT    16
#define P1_CHUNK  (256 * P1_EPT)                   // 4096 edges per block

__device__ __forceinline__ float lrelu(float v) { return v > 0.f ? v : NEG * v; }

__device__ __forceinline__ float readlane_f(float v, int l) {
  return __int_as_float(__builtin_amdgcn_readlane(__float_as_int(v), l));
}

// ---------------- CSR build (edges sorted by dst) ----------------

__global__ __launch_bounds__(256) void hist_k(const int* __restrict__ ei,
                                              int* __restrict__ deg) {
  int i = blockIdx.x * 256 + threadIdx.x;
  if (i >= ET) return;
  int dst = i < NE ? ei[NE + i] : i - NE;
  atomicAdd(&deg[dst], 1);
}

__global__ __launch_bounds__(SCAN_T) void scan_bsums_k(const int* __restrict__ deg,
                                                       int* __restrict__ bsum) {
  __shared__ int red[SCAN_T];
  int b = blockIdx.x, t = threadIdx.x;
  int base = b * SCAN_CHUNK + t * SCAN_ELEM;
  int s = 0;
#pragma unroll
  for (int i = 0; i < SCAN_ELEM; ++i) {
    int idx = base + i;
    if (idx < NN) s += deg[idx];
  }
  red[t] = s;
  __syncthreads();
  for (int off = SCAN_T / 2; off; off >>= 1) {
    if (t < off) red[t] += red[t + off];
    __syncthreads();
  }
  if (t == 0) bsum[b] = red[0];
}

__global__ __launch_bounds__(64) void scan_bbase_k(const int* __restrict__ bsum,
                                                   int* __restrict__ bbase) {
  int t = threadIdx.x;
  int v = (t < SCAN_NB) ? bsum[t] : 0;
  int inc = v;
  for (int off = 1; off < 64; off <<= 1) {
    int n = __shfl_up(inc, off);
    if (t >= off) inc += n;
  }
  if (t < SCAN_NB) bbase[t] = inc - v;
}

__global__ __launch_bounds__(SCAN_T) void scan_final_k(
    const int* __restrict__ deg, const int* __restrict__ bbase,
    int* __restrict__ rowptr, int* __restrict__ cursor) {
  __shared__ int tsum[SCAN_T];
  int b = blockIdx.x, t = threadIdx.x;
  int base = b * SCAN_CHUNK + t * SCAN_ELEM;
  int loc[SCAN_ELEM];
  int s = 0;
#pragma unroll
  for (int i = 0; i < SCAN_ELEM; ++i) {
    int idx = base + i;
    int v = (idx < NN) ? deg[idx] : 0;
    loc[i] = s;
    s += v;
  }
  tsum[t] = s;
  __syncthreads();
  for (int off = 1; off < SCAN_T; off <<= 1) {
    int v = tsum[t];
    int add = (t >= off) ? tsum[t - off] : 0;
    __syncthreads();
    tsum[t] = v + add;
    __syncthreads();
  }
  int tbase = bbase[b] + (t ? tsum[t - 1] : 0);
#pragma unroll
  for (int i = 0; i < SCAN_ELEM; ++i) {
    int idx = base + i;
    if (idx < NN) {
      int r = tbase + loc[i];
      rowptr[idx] = r;
      cursor[idx] = r;
    }
  }
  if (b == gridDim.x - 1 && t == SCAN_T - 1) rowptr[NN] = bbase[b] + tsum[SCAN_T - 1];
}

// staging cursors: one per bucket, init = CSR offset of bucket start
__global__ __launch_bounds__(512) void bcur_init_k(const int* __restrict__ rowptr,
                                                   int* __restrict__ bcur) {
  int b = threadIdx.x + blockIdx.x * 512;
  if (b < NBUK) bcur[b] = rowptr[b << BSPAN_LOG];
}

// phase 1: partition edges into dst-buckets. LDS histogram -> one global
// reservation per bucket per block -> contiguous staging runs (8B int2).
__global__ __launch_bounds__(256) void part1_k(const int* __restrict__ ei,
                                               int* __restrict__ bcur,
                                               int2* __restrict__ stage) {
  __shared__ int hist[NBUK];
  __shared__ int base[NBUK];
  int t = threadIdx.x;
  for (int b = t; b < NBUK; b += 256) hist[b] = 0;
  __syncthreads();
  int chunk = blockIdx.x * P1_CHUNK;
  int myb[P1_EPT], myr[P1_EPT], mys[P1_EPT], myd[P1_EPT];
#pragma unroll
  for (int it = 0; it < P1_EPT; ++it) {
    int i = chunk + it * 256 + t;
    bool v = i < ET;
    int src = 0, dst = 0;
    if (v) {
      src = i < NE ? ei[i] : i - NE;
      dst = i < NE ? ei[NE + i] : i - NE;
    }
    myb[it] = v ? (dst >> BSPAN_LOG) : -1;
    mys[it] = src;
    myd[it] = dst;
    myr[it] = v ? atomicAdd(&hist[dst >> BSPAN_LOG], 1) : 0;
  }
  __syncthreads();
  for (int b = t; b < NBUK; b += 256)
    base[b] = hist[b] ? atomicAdd(&bcur[b], hist[b]) : 0;
  __syncthreads();
#pragma unroll
  for (int it = 0; it < P1_EPT; ++it)
    if (myb[it] >= 0)
      stage[base[myb[it]] + myr[it]] = make_int2(mys[it], myd[it]);
}

// phase 2: one block per bucket -> the ~17KB esrc window stays on one XCD L2
__global__ __launch_bounds__(256) void part2_k(const int2* __restrict__ stage,
                                               const int* __restrict__ rowptr,
                                               int* __restrict__ cursor,
                                               int* __restrict__ esrc) {
  int b = blockIdx.x;
  int s = rowptr[b << BSPAN_LOG];
  int e = rowptr[min((b + 1) << BSPAN_LOG, NN)];
  for (int i = s + threadIdx.x; i < e; i += 256) {
    int2 p = stage[i];
    int pos = atomicAdd(&cursor[p.y], 1);
    esrc[pos] = p.x;
  }
}

// ---------------- GEMM + attention logits ----------------
// h = (x*scale+shift) @ W ; alpha_s = h.as ; alpha_d = h.ad
// BN affine folded into LDS copy: WlT = (W*scale)^T, cvec = shift@W.
// W TRANSPOSED in LDS, STRIDE = K+1 (odd => banks (f+k)%32, 2-way = free).
// 4 rows/wave; the wave's 4 x-rows (512 floats) are loaded COOPERATIVELY
// (8 floats/lane, 2 coalesced b128) then broadcast in the inner loop with
// v_readlane at compile-time lane L = r*16+g (SALU, co-issues; SGPR operand
// to v_fmac is free). Inner loop: zero VMEM, zero SMEM, no barrier.
// NOTE R5: 8 rows/wave -> 256 VGPR -> occupancy collapse. Keep 4 rows.
// NOTE R7: stride K+4 was an 8-way bank conflict (4.8M conflict cycles).
template <int K>
__global__ __launch_bounds__(256) void gemm_att(
    const float* __restrict__ x, const float* __restrict__ scale,
    const float* __restrict__ shift, const float* __restrict__ W,
    const float* __restrict__ a_s, const float* __restrict__ a_d,
    float* __restrict__ h, float* __restrict__ sv_out, float* __restrict__ dv_out) {
  constexpr int STRIDE = K + 1;
  constexpr int XPL = 4 * K / 64;          // floats per lane (K=128 -> 8)
  constexpr int NV4 = XPL / 4;             // float4 loads per lane
  __shared__ float WlT[HID * STRIDE];
  __shared__ float cvec[HID];
  int tid = threadIdx.x;
  if (tid < HID) cvec[tid] = 0.f;
  __syncthreads();
  if (scale != nullptr) {
    float clocal = 0.f;
    for (int i = tid; i < K * HID; i += 256) {
      int k = i >> 6, f = i & 63;            // HID == 64; k wave-uniform
      float w = W[i];                        // coalesced
      clocal += shift[k] * w;
      WlT[f * STRIDE + k] = w * scale[k];
    }
    atomicAdd(&cvec[tid & 63], clocal);      // feature index fixed per thread
  } else {
    for (int i = tid; i < K * HID; i += 256) {
      int k = i >> 6, f = i & 63;
      WlT[f * STRIDE + k] = W[i];
    }
  }
  __syncthreads();

  int lane = tid & 63;
  int wid = tid >> 6;
  int row0 = blockIdx.x * 16 + wid * 4;     // NN % 16 == 0, no tail
  float cv = cvec[lane];
  float acc[4] = {cv, cv, cv, cv};

  // cooperative x load: flat = lane*XPL + (v*4+j) over rows row0..row0+3
  float xr[XPL];
  const float* xbase = x + (size_t)row0 * K;
#pragma unroll
  for (int v = 0; v < NV4; ++v)
    *(float4*)&xr[v * 4] = *(const float4*)(xbase + lane * XPL + v * 4);

  const float* wrow = &WlT[lane * STRIDE];
#pragma unroll
  for (int g = 0; g < 16; ++g) {            // K/XPL == 16 for both K
    float wv[XPL];
#pragma unroll
    for (int v = 0; v < NV4; ++v)
      *(float4*)&wv[v * 4] = *(const float4*)(wrow + g * XPL + v * 4);
#pragma unroll
    for (int r = 0; r < 4; ++r) {
#pragma unroll
      for (int m = 0; m < XPL; ++m)
        acc[r] = fmaf(readlane_f(xr[m], r * 16 + g), wv[m], acc[r]);
    }
  }

  float asl = a_s[lane], adl = a_d[lane];
  float s0 = acc[0] * asl, d0 = acc[0] * adl;
  float s1 = acc[1] * asl, d1 = acc[1] * adl;
  float s2 = acc[2] * asl, d2 = acc[2] * adl;
  float s3 = acc[3] * asl, d3 = acc[3] * adl;
  h[(size_t)(row0 + 0) * HID + lane] = acc[0];
  h[(size_t)(row0 + 1) * HID + lane] = acc[1];
  h[(size_t)(row0 + 2) * HID + lane] = acc[2];
  h[(size_t)(row0 + 3) * HID + lane] = acc[3];
  for (int o = 32; o; o >>= 1) {
    s0 += __shfl_xor(s0, o); d0 += __shfl_xor(d0, o);
    s1 += __shfl_xor(s1, o); d1 += __shfl_xor(d1, o);
    s2 += __shfl_xor(s2, o); d2 += __shfl_xor(d2, o);
    s3 += __shfl_xor(s3, o); d3 += __shfl_xor(d3, o);
  }
  if (lane == 0) {
    sv_out[row0 + 0] = s0; dv_out[row0 + 0] = d0;
    sv_out[row0 + 1] = s1; dv_out[row0 + 1] = d1;
    sv_out[row0 + 2] = s2; dv_out[row0 + 2] = d2;
    sv_out[row0 + 3] = s3; dv_out[row0 + 3] = d3;
  }
}

// ---------------- fused per-dst GAT aggregation ----------------
// wave per node. Fast path (deg<=64): lane=edge computes alpha in parallel,
// then gather loop broadcasts src/alpha via v_readlane. 2048 blocks + 4-deep
// unroll is the proven config (4096 + 8-deep regressed 127->171 us).
__global__ __launch_bounds__(256) void gat_agg_k(
    const int* __restrict__ rowptr, const int* __restrict__ esrc,
    const float* __restrict__ s, const float* __restrict__ d,
    const float* __restrict__ h, const float* __restrict__ bias,
    float* __restrict__ y, float* __restrict__ fsum, float* __restrict__ fsq) {
  __shared__ float lsum[HID], lsq[HID];
  int tid = threadIdx.x;
  if (tid < HID) { lsum[tid] = 0.f; lsq[tid] = 0.f; }
  __syncthreads();
  int lane = tid & 63;
  float bv = bias[lane];
  float ls = 0.f, lq = 0.f;
  int wave = blockIdx.x * 4 + (tid >> 6);
  int nwaves = gridDim.x * 4;
  for (int node = wave; node < NN; node += nwaves) {
    int start = rowptr[node], end = rowptr[node + 1];
    int deg = end - start;
    float dn = d[node];
    float acc = 0.f;
    if (deg <= 64) {
      int j = start + (lane < deg ? lane : 0);
      int sj = esrc[j];                         // coalesced
      float e = lrelu(s[sj] + dn);
      float ev = (lane < deg) ? e : -INFINITY;
      float m = ev;
      for (int o = 32; o; o >>= 1) m = fmaxf(m, __shfl_xor(m, o));
      float w = (lane < deg) ? __expf(e - m) : 0.f;
      float wsum = w;
      for (int o = 32; o; o >>= 1) wsum += __shfl_xor(wsum, o);
      float alpha = w / wsum;
      int t = 0;
      for (; t + 3 < deg; t += 4) {
        int p0 = __builtin_amdgcn_readlane(sj, t + 0);
        int p1 = __builtin_amdgcn_readlane(sj, t + 1);
        int p2 = __builtin_amdgcn_readlane(sj, t + 2);
        int p3 = __builtin_amdgcn_readlane(sj, t + 3);
        float b0 = readlane_f(alpha, t + 0);
        float b1 = readlane_f(alpha, t + 1);
        float b2 = readlane_f(alpha, t + 2);
        float b3 = readlane_f(alpha, t + 3);
        float h0 = h[(size_t)p0 * HID + lane];
        float h1 = h[(size_t)p1 * HID + lane];
        float h2 = h[(size_t)p2 * HID + lane];
        float h3 = h[(size_t)p3 * HID + lane];
        acc = fmaf(b0, h0, acc);
        acc = fmaf(b1, h1, acc);
        acc = fmaf(b2, h2, acc);
        acc = fmaf(b3, h3, acc);
      }
      for (; t < deg; ++t) {
        int p0 = __builtin_amdgcn_readlane(sj, t);
        float b0 = readlane_f(alpha, t);
        acc = fmaf(b0, h[(size_t)p0 * HID + lane], acc);
      }
    } else {
      // generic chunked path
      float m = -INFINITY;
      for (int j = start + lane; j < end; j += 64)
        m = fmaxf(m, lrelu(s[esrc[j]] + dn));
      for (int o = 32; o; o >>= 1) m = fmaxf(m, __shfl_xor(m, o));
      float wsum = 0.f;
      for (int j = start + lane; j < end; j += 64)
        wsum += __expf(lrelu(s[esrc[j]] + dn) - m);
      for (int o = 32; o; o >>= 1) wsum += __shfl_xor(wsum, o);
      float inv = 1.0f / wsum;
      for (int cb = start; cb < end; cb += 64) {
        int cc = min(64, end - cb);
        int j = cb + (lane < cc ? lane : 0);
        int sj = esrc[j];
        float alpha = __expf(lrelu(s[sj] + dn) - m) * inv;
        for (int t = 0; t < cc; ++t) {
          int p0 = __builtin_amdgcn_readlane(sj, t);
          float b0 = readlane_f(alpha, t);
          acc = fmaf(b0, h[(size_t)p0 * HID + lane], acc);
        }
      }
    }
    float v = fmaxf(acc + bv, 0.f);
    y[(size_t)node * HID + lane] = v;
    ls += v;
    lq += v * v;
  }
  atomicAdd(&lsum[lane], ls);
  atomicAdd(&lsq[lane], lq);
  __syncthreads();
  if (tid < HID) { atomicAdd(&fsum[tid], lsum[tid]); atomicAdd(&fsq[tid], lsq[tid]); }
}

__global__ void bn_params(const float* __restrict__ fsum, const float* __restrict__ fsq,
                          const float* __restrict__ g, const float* __restrict__ b,
                          float* __restrict__ a_out, float* __restrict__ c_out) {
  int f = threadIdx.x;
  float m = fsum[f] * (1.0f / NN);
  float v = fsq[f] * (1.0f / NN) - m * m;
  float a = g[f] * rsqrtf(v + BN_EPS);
  a_out[f] = a;
  c_out[f] = b[f] - m * a;
}

// segmented pool over sorted batch: wave per contiguous node range; register
// accumulate per graph run; one 64-lane atomic flush per run. Also counts.
__global__ __launch_bounds__(256) void pool_k(
    const float* __restrict__ y, const int* __restrict__ batch,
    float* __restrict__ pooled, float* __restrict__ cnt) {
  int wid = blockIdx.x * 4 + (threadIdx.x >> 6);
  int lane = threadIdx.x & 63;
  int nw = gridDim.x * 4;
  int per = (NN + nw - 1) / nw;
  int lo = wid * per, hi = min(lo + per, NN);
  if (lo >= hi) return;
  int g = batch[lo];
  float acc = 0.f, c = 0.f;
  for (int node = lo; node < hi; ++node) {
    int bg = batch[node];                 // wave-uniform
    if (bg != g) {
      atomicAdd(&pooled[g * HID + lane], acc);
      if (lane == 0) atomicAdd(&cnt[g], c);
      g = bg; acc = 0.f; c = 0.f;
    }
    acc += y[(size_t)node * HID + lane];
    c += 1.f;
  }
  atomicAdd(&pooled[g * HID + lane], acc);
  if (lane == 0) atomicAdd(&cnt[g], c);
}

// one block (64 threads) per graph: BN2 affine + mean + full MLP head
__global__ __launch_bounds__(64) void mlp_head(
    const float* __restrict__ pooled, const float* __restrict__ cnt,
    const float* __restrict__ aP, const float* __restrict__ cP,
    const float* __restrict__ m1w, const float* __restrict__ m1b,
    const float* __restrict__ m2w, const float* __restrict__ m2b,
    const float* __restrict__ m3w, const float* __restrict__ m3b,
    const float* __restrict__ m4w, const float* __restrict__ m4b,
    float* __restrict__ out) {
  __shared__ float p[64], z1[64], z2[16], z3[8];
  int g = blockIdx.x, f = threadIdx.x;
  float cv = fmaxf(cnt[g], 1.0f);
  p[f] = aP[f] * pooled[g * 64 + f] / cv + cP[f];
  __syncthreads();
  float a1 = m1b[f];
  for (int k = 0; k < 64; ++k) a1 += p[k] * m1w[k * 64 + f];
  z1[f] = fmaxf(a1, 0.f);
  __syncthreads();
  if (f < 16) {
    float a2 = m2b[f];
    for (int k = 0; k < 64; ++k) a2 += z1[k] * m2w[k * 16 + f];
    z2[f] = fmaxf(a2, 0.f);
  }
  __syncthreads();
  if (f < 8) {
    float a3 = m3b[f];
    for (int k = 0; k < 16; ++k) a3 += z2[k] * m3w[k * 8 + f];
    z3[f] = fmaxf(a3, 0.f);
  }
  __syncthreads();
  if (f < 10) {
    float a4 = m4b[f];
    for (int k = 0; k < 8; ++k) a4 += z3[k] * m4w[k * 10 + f];
    out[g * 10 + f] = a4;
  }
}

extern "C" void kernel_launch(void* const* d_in, const int* in_sizes, int n_in,
                              void* d_out, int out_size, void* d_ws, size_t ws_size,
                              hipStream_t stream) {
  const float* x   = (const float*)d_in[0];
  const int*   ei  = (const int*)d_in[1];
  const int*   bat = (const int*)d_in[2];
  const float* W1  = (const float*)d_in[3];
  const float* as1 = (const float*)d_in[4];
  const float* ad1 = (const float*)d_in[5];
  const float* b1  = (const float*)d_in[6];
  const float* W2  = (const float*)d_in[7];
  const float* as2 = (const float*)d_in[8];
  const float* ad2 = (const float*)d_in[9];
  const float* b2  = (const float*)d_in[10];
  const float* bng = (const float*)d_in[11];
  const float* bnb = (const float*)d_in[12];
  const float* m1w = (const float*)d_in[13];
  const float* m1b = (const float*)d_in[14];
  const float* m2w = (const float*)d_in[15];
  const float* m2b = (const float*)d_in[16];
  const float* m3w = (const float*)d_in[17];
  const float* m3b = (const float*)d_in[18];
  const float* m4w = (const float*)d_in[19];
  const float* m4b = (const float*)d_in[20];
  float* out = (float*)d_out;

  float* ws = (float*)d_ws;
  size_t off = 0;
  float* hbuf = ws + off; off += (size_t)NN * HID;   // GEMM output h (aliases stage)
  float* ybuf = ws + off; off += (size_t)NN * HID;   // layer output y
  float* sbuf = ws + off; off += NN;                 // alpha_s
  float* dbuf = ws + off; off += NN;                 // alpha_d
  int* deg    = (int*)(ws + off); off += NN;
  int* rowptr = (int*)(ws + off); off += NN + 1;
  int* cursor = (int*)(ws + off); off += NN;
  int* esrc   = (int*)(ws + off); off += ET;         // CSR: src per dst-sorted edge
  int* bsum   = (int*)(ws + off); off += SCAN_NB;
  int* bbase  = (int*)(ws + off); off += SCAN_NB;
  int* bcur   = (int*)(ws + off); off += NBUK;
  float* fsum = ws + off; off += HID;
  float* fsq  = ws + off; off += HID;
  float* aP   = ws + off; off += HID;                // BN scale
  float* cP   = ws + off; off += HID;                // BN shift
  float* pooled = ws + off; off += (size_t)NG * HID; // raw per-graph sums
  float* cnt  = ws + off; off += NG;
  int2* stage = (int2*)hbuf;  // 13.6MB staging aliases hbuf (free until gemm1)

  dim3 b256(256);
  const int gemmGrid = NN / 16;                      // 6250, exact
  const int edgeGrid = (ET + 255) / 256;
  const int p1Grid = (ET + P1_CHUNK - 1) / P1_CHUNK; // 416
  const int aggGrid = 2048;

  // ---------- CSR build (shared by both layers) ----------
  hipMemsetAsync(deg, 0, NN * 4, stream);
  hist_k<<<edgeGrid, b256, 0, stream>>>(ei, deg);
  scan_bsums_k<<<SCAN_NB, SCAN_T, 0, stream>>>(deg, bsum);
  scan_bbase_k<<<1, 64, 0, stream>>>(bsum, bbase);
  scan_final_k<<<SCAN_NB, SCAN_T, 0, stream>>>(deg, bbase, rowptr, cursor);
  bcur_init_k<<<1, 512, 0, stream>>>(rowptr, bcur);
  part1_k<<<p1Grid, b256, 0, stream>>>(ei, bcur, stage);
  part2_k<<<NBUK, b256, 0, stream>>>(stage, rowptr, cursor, esrc);

  // ---------- layer 1 ----------
  gemm_att<INF_><<<gemmGrid, b256, 0, stream>>>(x, nullptr, nullptr, W1, as1, ad1,
                                                hbuf, sbuf, dbuf);
  hipMemsetAsync(fsum, 0, HID * 4, stream);
  hipMemsetAsync(fsq, 0, HID * 4, stream);
  gat_agg_k<<<aggGrid, b256, 0, stream>>>(rowptr, esrc, sbuf, dbuf, hbuf, b1,
                                          ybuf, fsum, fsq);
  bn_params<<<1, 64, 0, stream>>>(fsum, fsq, bng, bnb, aP, cP);

  // ---------- layer 2 (BN affine folded into GEMM weight copy) ----------
  gemm_att<HID><<<gemmGrid, b256, 0, stream>>>(ybuf, aP, cP, W2, as2, ad2,
                                               hbuf, sbuf, dbuf);
  hipMemsetAsync(fsum, 0, HID * 4, stream);
  hipMemsetAsync(fsq, 0, HID * 4, stream);
  gat_agg_k<<<aggGrid, b256, 0, stream>>>(rowptr, esrc, sbuf, dbuf, hbuf, b2,
                                          ybuf, fsum, fsq);
  bn_params<<<1, 64, 0, stream>>>(fsum, fsq, bng, bnb, aP, cP);

  // ---------- pool (segmented, sorted batch) + MLP ----------
  hipMemsetAsync(pooled, 0, (size_t)NG * HID * 4, stream);
  hipMemsetAsync(cnt, 0, NG * 4, stream);
  pool_k<<<1024, b256, 0, stream>>>(ybuf, bat, pooled, cnt);
  mlp_head<<<NG, 64, 0, stream>>>(pooled, cnt, aP, cP, m1w, m1b, m2w, m2b,
                                  m3w, m3b, m4w, m4b, out);
}

// Round 9
// 590.833 us; speedup vs baseline: 1.0651x; 1.0651x over previous
//
#include <hip/hip_runtime.h>

// Problem constants (match reference)
#define NN   100000              // nodes
#define NE   1600000             // edges before self loops
#define ET   (NE + NN)           // edges incl. self loops
#define INF_ 128                 // input features
#define HID  64                  // hidden
#define NG   256                 // graphs
#define BN_EPS 1e-5f
#define NEG  0.2f

// hierarchical scan geometry
#define SCAN_T     256
#define SCAN_ELEM  8
#define SCAN_CHUNK (SCAN_T * SCAN_ELEM)
#define SCAN_NB    ((NN + SCAN_CHUNK - 1) / SCAN_CHUNK)  // 49 (<= 64, fits a wave)

// bucket partition geometry (CSR fill)
#define BSPAN_LOG 8
#define BSPAN     (1 << BSPAN_LOG)                 // 256 dst nodes per bucket
#define NBUK      ((NN + BSPAN - 1) / BSPAN)       // 391
#define P1_EPT    16
#define P1_CHUNK  (256 * P1_EPT)                   // 4096 edges per block

__device__ __forceinline__ float lrelu(float v) { return v > 0.f ? v : NEG * v; }

__device__ __forceinline__ float readlane_f(float v, int l) {
  return __int_as_float(__builtin_amdgcn_readlane(__float_as_int(v), l));
}

// ---------------- CSR build (edges sorted by dst) ----------------

__global__ __launch_bounds__(256) void hist_k(const int* __restrict__ ei,
                                              int* __restrict__ deg) {
  int i = blockIdx.x * 256 + threadIdx.x;
  if (i >= ET) return;
  int dst = i < NE ? ei[NE + i] : i - NE;
  atomicAdd(&deg[dst], 1);
}

__global__ __launch_bounds__(SCAN_T) void scan_bsums_k(const int* __restrict__ deg,
                                                       int* __restrict__ bsum) {
  __shared__ int red[SCAN_T];
  int b = blockIdx.x, t = threadIdx.x;
  int base = b * SCAN_CHUNK + t * SCAN_ELEM;
  int s = 0;
#pragma unroll
  for (int i = 0; i < SCAN_ELEM; ++i) {
    int idx = base + i;
    if (idx < NN) s += deg[idx];
  }
  red[t] = s;
  __syncthreads();
  for (int off = SCAN_T / 2; off; off >>= 1) {
    if (t < off) red[t] += red[t + off];
    __syncthreads();
  }
  if (t == 0) bsum[b] = red[0];
}

__global__ __launch_bounds__(64) void scan_bbase_k(const int* __restrict__ bsum,
                                                   int* __restrict__ bbase) {
  int t = threadIdx.x;
  int v = (t < SCAN_NB) ? bsum[t] : 0;
  int inc = v;
  for (int off = 1; off < 64; off <<= 1) {
    int n = __shfl_up(inc, off);
    if (t >= off) inc += n;
  }
  if (t < SCAN_NB) bbase[t] = inc - v;
}

__global__ __launch_bounds__(SCAN_T) void scan_final_k(
    const int* __restrict__ deg, const int* __restrict__ bbase,
    int* __restrict__ rowptr, int* __restrict__ cursor) {
  __shared__ int tsum[SCAN_T];
  int b = blockIdx.x, t = threadIdx.x;
  int base = b * SCAN_CHUNK + t * SCAN_ELEM;
  int loc[SCAN_ELEM];
  int s = 0;
#pragma unroll
  for (int i = 0; i < SCAN_ELEM; ++i) {
    int idx = base + i;
    int v = (idx < NN) ? deg[idx] : 0;
    loc[i] = s;
    s += v;
  }
  tsum[t] = s;
  __syncthreads();
  for (int off = 1; off < SCAN_T; off <<= 1) {
    int v = tsum[t];
    int add = (t >= off) ? tsum[t - off] : 0;
    __syncthreads();
    tsum[t] = v + add;
    __syncthreads();
  }
  int tbase = bbase[b] + (t ? tsum[t - 1] : 0);
#pragma unroll
  for (int i = 0; i < SCAN_ELEM; ++i) {
    int idx = base + i;
    if (idx < NN) {
      int r = tbase + loc[i];
      rowptr[idx] = r;
      cursor[idx] = r;
    }
  }
  if (b == gridDim.x - 1 && t == SCAN_T - 1) rowptr[NN] = bbase[b] + tsum[SCAN_T - 1];
}

// staging cursors (one per bucket, init = CSR offset of bucket start);
// also zero-inits fsum/fsq for the layer-1 aggregation (folded memsets).
__global__ __launch_bounds__(512) void bcur_init_k(const int* __restrict__ rowptr,
                                                   int* __restrict__ bcur,
                                                   float* __restrict__ fsum,
                                                   float* __restrict__ fsq) {
  int b = threadIdx.x + blockIdx.x * 512;
  if (b < NBUK) bcur[b] = rowptr[b << BSPAN_LOG];
  if (b < HID) { fsum[b] = 0.f; fsq[b] = 0.f; }
}

// phase 1: partition edges into dst-buckets. LDS histogram -> one global
// reservation per bucket per block -> contiguous staging runs (8B int2).
__global__ __launch_bounds__(256) void part1_k(const int* __restrict__ ei,
                                               int* __restrict__ bcur,
                                               int2* __restrict__ stage) {
  __shared__ int hist[NBUK];
  __shared__ int base[NBUK];
  int t = threadIdx.x;
  for (int b = t; b < NBUK; b += 256) hist[b] = 0;
  __syncthreads();
  int chunk = blockIdx.x * P1_CHUNK;
  int myb[P1_EPT], myr[P1_EPT], mys[P1_EPT], myd[P1_EPT];
#pragma unroll
  for (int it = 0; it < P1_EPT; ++it) {
    int i = chunk + it * 256 + t;
    bool v = i < ET;
    int src = 0, dst = 0;
    if (v) {
      src = i < NE ? ei[i] : i - NE;
      dst = i < NE ? ei[NE + i] : i - NE;
    }
    myb[it] = v ? (dst >> BSPAN_LOG) : -1;
    mys[it] = src;
    myd[it] = dst;
    myr[it] = v ? atomicAdd(&hist[dst >> BSPAN_LOG], 1) : 0;
  }
  __syncthreads();
  for (int b = t; b < NBUK; b += 256)
    base[b] = hist[b] ? atomicAdd(&bcur[b], hist[b]) : 0;
  __syncthreads();
#pragma unroll
  for (int it = 0; it < P1_EPT; ++it)
    if (myb[it] >= 0)
      stage[base[myb[it]] + myr[it]] = make_int2(mys[it], myd[it]);
}

// phase 2: one block per bucket -> the ~17KB esrc window stays on one XCD L2
__global__ __launch_bounds__(256) void part2_k(const int2* __restrict__ stage,
                                               const int* __restrict__ rowptr,
                                               int* __restrict__ cursor,
                                               int* __restrict__ esrc) {
  int b = blockIdx.x;
  int s = rowptr[b << BSPAN_LOG];
  int e = rowptr[min((b + 1) << BSPAN_LOG, NN)];
  for (int i = s + threadIdx.x; i < e; i += 256) {
    int2 p = stage[i];
    int pos = atomicAdd(&cursor[p.y], 1);
    esrc[pos] = p.x;
  }
}

// ---------------- GEMM + attention logits ----------------
// h = (x*scale+shift) @ W ; alpha_s = h.as ; alpha_d = h.ad
// BN affine folded into LDS copy: WlT = (W*scale)^T, cvec = shift@W.
// W TRANSPOSED in LDS, STRIDE = K+1 (odd => banks (f+k)%32, 2-way = free).
// 4 rows/wave; the wave's 4 x-rows loaded cooperatively then broadcast via
// v_readlane. NOTE R5: 8 rows/wave -> 256 VGPR -> occupancy collapse.
// NOTE R7: stride K+4 was an 8-way bank conflict (4.8M conflict cycles).
template <int K>
__global__ __launch_bounds__(256) void gemm_att(
    const float* __restrict__ x, const float* __restrict__ scale,
    const float* __restrict__ shift, const float* __restrict__ W,
    const float* __restrict__ a_s, const float* __restrict__ a_d,
    float* __restrict__ h, float* __restrict__ sv_out, float* __restrict__ dv_out) {
  constexpr int STRIDE = K + 1;
  constexpr int XPL = 4 * K / 64;          // floats per lane (K=128 -> 8)
  constexpr int NV4 = XPL / 4;             // float4 loads per lane
  __shared__ float WlT[HID * STRIDE];
  __shared__ float cvec[HID];
  int tid = threadIdx.x;
  if (tid < HID) cvec[tid] = 0.f;
  __syncthreads();
  if (scale != nullptr) {
    float clocal = 0.f;
    for (int i = tid; i < K * HID; i += 256) {
      int k = i >> 6, f = i & 63;            // HID == 64; k wave-uniform
      float w = W[i];                        // coalesced
      clocal += shift[k] * w;
      WlT[f * STRIDE + k] = w * scale[k];
    }
    atomicAdd(&cvec[tid & 63], clocal);      // feature index fixed per thread
  } else {
    for (int i = tid; i < K * HID; i += 256) {
      int k = i >> 6, f = i & 63;
      WlT[f * STRIDE + k] = W[i];
    }
  }
  __syncthreads();

  int lane = tid & 63;
  int wid = tid >> 6;
  int row0 = blockIdx.x * 16 + wid * 4;     // NN % 16 == 0, no tail
  float cv = cvec[lane];
  float acc[4] = {cv, cv, cv, cv};

  // cooperative x load: flat = lane*XPL + (v*4+j) over rows row0..row0+3
  float xr[XPL];
  const float* xbase = x + (size_t)row0 * K;
#pragma unroll
  for (int v = 0; v < NV4; ++v)
    *(float4*)&xr[v * 4] = *(const float4*)(xbase + lane * XPL + v * 4);

  const float* wrow = &WlT[lane * STRIDE];
#pragma unroll
  for (int g = 0; g < 16; ++g) {            // K/XPL == 16 for both K
    float wv[XPL];
#pragma unroll
    for (int v = 0; v < NV4; ++v)
      *(float4*)&wv[v * 4] = *(const float4*)(wrow + g * XPL + v * 4);
#pragma unroll
    for (int r = 0; r < 4; ++r) {
#pragma unroll
      for (int m = 0; m < XPL; ++m)
        acc[r] = fmaf(readlane_f(xr[m], r * 16 + g), wv[m], acc[r]);
    }
  }

  float asl = a_s[lane], adl = a_d[lane];
  float s0 = acc[0] * asl, d0 = acc[0] * adl;
  float s1 = acc[1] * asl, d1 = acc[1] * adl;
  float s2 = acc[2] * asl, d2 = acc[2] * adl;
  float s3 = acc[3] * asl, d3 = acc[3] * adl;
  h[(size_t)(row0 + 0) * HID + lane] = acc[0];
  h[(size_t)(row0 + 1) * HID + lane] = acc[1];
  h[(size_t)(row0 + 2) * HID + lane] = acc[2];
  h[(size_t)(row0 + 3) * HID + lane] = acc[3];
  for (int o = 32; o; o >>= 1) {
    s0 += __shfl_xor(s0, o); d0 += __shfl_xor(d0, o);
    s1 += __shfl_xor(s1, o); d1 += __shfl_xor(d1, o);
    s2 += __shfl_xor(s2, o); d2 += __shfl_xor(d2, o);
    s3 += __shfl_xor(s3, o); d3 += __shfl_xor(d3, o);
  }
  if (lane == 0) {
    sv_out[row0 + 0] = s0; dv_out[row0 + 0] = d0;
    sv_out[row0 + 1] = s1; dv_out[row0 + 1] = d1;
    sv_out[row0 + 2] = s2; dv_out[row0 + 2] = d2;
    sv_out[row0 + 3] = s3; dv_out[row0 + 3] = d3;
  }
}

// ---------------- fused per-dst GAT aggregation ----------------
// wave per node. Softmax phase: lane=edge (alpha=0 for lane>=deg).
// Gather phase: DUAL-EDGE float2 layout -- lanes 0-31 take the even-slot
// edge, lanes 32-63 the odd-slot edge; each lane loads float2 of features
// (2L, 2L+1). 4 loads in flight now cover 8 edges (2x the memory-level
// parallelism of the single-edge layout at the same unroll depth).
// Over-read slots (>= deg) have alpha==0 and hit the cached slot-0 row.
__global__ __launch_bounds__(256) void gat_agg_k(
    const int* __restrict__ rowptr, const int* __restrict__ esrc,
    const float* __restrict__ s, const float* __restrict__ d,
    const float* __restrict__ h, const float* __restrict__ bias,
    float* __restrict__ y, float* __restrict__ fsum, float* __restrict__ fsq) {
  __shared__ float lsum[HID], lsq[HID];
  int tid = threadIdx.x;
  if (tid < HID) { lsum[tid] = 0.f; lsq[tid] = 0.f; }
  __syncthreads();
  int lane = tid & 63;
  int half = lane >> 5;
  int fl = (lane & 31) * 2;
  float2 bv = *(const float2*)&bias[fl];
  float2 ls = {0.f, 0.f}, lq = {0.f, 0.f};
  int wave = blockIdx.x * 4 + (tid >> 6);
  int nwaves = gridDim.x * 4;
  for (int node = wave; node < NN; node += nwaves) {
    int start = rowptr[node], end = rowptr[node + 1];
    int deg = end - start;
    float dn = d[node];
    float2 acc = {0.f, 0.f};
    if (deg <= 64) {
      int j = start + (lane < deg ? lane : 0);
      int sj = esrc[j];                         // coalesced
      float e = lrelu(s[sj] + dn);
      float ev = (lane < deg) ? e : -INFINITY;
      float m = ev;
      for (int o = 32; o; o >>= 1) m = fmaxf(m, __shfl_xor(m, o));
      float w = (lane < deg) ? __expf(e - m) : 0.f;
      float wsum = w;
      for (int o = 32; o; o >>= 1) wsum += __shfl_xor(wsum, o);
      float alpha = w / wsum;                   // 0 for slots >= deg
      for (int t = 0; t < deg; t += 8) {
#pragma unroll
        for (int i = 0; i < 4; ++i) {
          int e0 = t + 2 * i;
          int p0 = __builtin_amdgcn_readlane(sj, e0);
          int p1 = __builtin_amdgcn_readlane(sj, e0 + 1);
          float a0 = readlane_f(alpha, e0);
          float a1 = readlane_f(alpha, e0 + 1);
          int ps = half ? p1 : p0;
          float aw = half ? a1 : a0;
          float2 hv = *(const float2*)&h[(size_t)ps * HID + fl];
          acc.x = fmaf(aw, hv.x, acc.x);
          acc.y = fmaf(aw, hv.y, acc.y);
        }
      }
    } else {
      // generic chunked path (deg > 64): same dual-edge gather per chunk
      float m = -INFINITY;
      for (int j = start + lane; j < end; j += 64)
        m = fmaxf(m, lrelu(s[esrc[j]] + dn));
      for (int o = 32; o; o >>= 1) m = fmaxf(m, __shfl_xor(m, o));
      float wsum = 0.f;
      for (int j = start + lane; j < end; j += 64)
        wsum += __expf(lrelu(s[esrc[j]] + dn) - m);
      for (int o = 32; o; o >>= 1) wsum += __shfl_xor(wsum, o);
      float inv = 1.0f / wsum;
      for (int cb = start; cb < end; cb += 64) {
        int cc = min(64, end - cb);
        int j = cb + (lane < cc ? lane : 0);
        int sj = esrc[j];
        float alpha = (lane < cc) ? __expf(lrelu(s[sj] + dn) - m) * inv : 0.f;
        for (int t = 0; t < cc; t += 8) {
#pragma unroll
          for (int i = 0; i < 4; ++i) {
            int e0 = t + 2 * i;
            int p0 = __builtin_amdgcn_readlane(sj, e0);
            int p1 = __builtin_amdgcn_readlane(sj, e0 + 1);
            float a0 = readlane_f(alpha, e0);
            float a1 = readlane_f(alpha, e0 + 1);
            int ps = half ? p1 : p0;
            float aw = half ? a1 : a0;
            float2 hv = *(const float2*)&h[(size_t)ps * HID + fl];
            acc.x = fmaf(aw, hv.x, acc.x);
            acc.y = fmaf(aw, hv.y, acc.y);
          }
        }
      }
    }
    // cross-half combine: both halves end with the full per-feature sum
    acc.x += __shfl_xor(acc.x, 32);
    acc.y += __shfl_xor(acc.y, 32);
    float vx = fmaxf(acc.x + bv.x, 0.f);
    float vy = fmaxf(acc.y + bv.y, 0.f);
    if (half == 0) {
      *(float2*)&y[(size_t)node * HID + fl] = make_float2(vx, vy);
      ls.x += vx; ls.y += vy;
      lq.x += vx * vx; lq.y += vy * vy;
    }
  }
  if (lane < 32) {
    atomicAdd(&lsum[fl + 0], ls.x);
    atomicAdd(&lsum[fl + 1], ls.y);
    atomicAdd(&lsq[fl + 0], lq.x);
    atomicAdd(&lsq[fl + 1], lq.y);
  }
  __syncthreads();
  if (tid < HID) { atomicAdd(&fsum[tid], lsum[tid]); atomicAdd(&fsq[tid], lsq[tid]); }
}

// computes BN affine; re-zeroes fsum/fsq for the next consumer; optionally
// zero-inits pooled/cnt for the pooling stage (folded memsets).
__global__ void bn_params(float* __restrict__ fsum, float* __restrict__ fsq,
                          const float* __restrict__ g, const float* __restrict__ b,
                          float* __restrict__ a_out, float* __restrict__ c_out,
                          float* __restrict__ pooled_z, float* __restrict__ cnt_z) {
  int f = threadIdx.x;
  float m = fsum[f] * (1.0f / NN);
  float v = fsq[f] * (1.0f / NN) - m * m;
  float a = g[f] * rsqrtf(v + BN_EPS);
  a_out[f] = a;
  c_out[f] = b[f] - m * a;
  fsum[f] = 0.f;
  fsq[f] = 0.f;
  if (pooled_z != nullptr) {
    for (int i = f; i < NG * HID; i += 64) pooled_z[i] = 0.f;
    for (int i = f; i < NG; i += 64) cnt_z[i] = 0.f;
  }
}

// segmented pool over sorted batch: wave per contiguous node range; register
// accumulate per graph run; one 64-lane atomic flush per run. Also counts.
__global__ __launch_bounds__(256) void pool_k(
    const float* __restrict__ y, const int* __restrict__ batch,
    float* __restrict__ pooled, float* __restrict__ cnt) {
  int wid = blockIdx.x * 4 + (threadIdx.x >> 6);
  int lane = threadIdx.x & 63;
  int nw = gridDim.x * 4;
  int per = (NN + nw - 1) / nw;
  int lo = wid * per, hi = min(lo + per, NN);
  if (lo >= hi) return;
  int g = batch[lo];
  float acc = 0.f, c = 0.f;
  for (int node = lo; node < hi; ++node) {
    int bg = batch[node];                 // wave-uniform
    if (bg != g) {
      atomicAdd(&pooled[g * HID + lane], acc);
      if (lane == 0) atomicAdd(&cnt[g], c);
      g = bg; acc = 0.f; c = 0.f;
    }
    acc += y[(size_t)node * HID + lane];
    c += 1.f;
  }
  atomicAdd(&pooled[g * HID + lane], acc);
  if (lane == 0) atomicAdd(&cnt[g], c);
}

// one block (64 threads) per graph: BN2 affine + mean + full MLP head
__global__ __launch_bounds__(64) void mlp_head(
    const float* __restrict__ pooled, const float* __restrict__ cnt,
    const float* __restrict__ aP, const float* __restrict__ cP,
    const float* __restrict__ m1w, const float* __restrict__ m1b,
    const float* __restrict__ m2w, const float* __restrict__ m2b,
    const float* __restrict__ m3w, const float* __restrict__ m3b,
    const float* __restrict__ m4w, const float* __restrict__ m4b,
    float* __restrict__ out) {
  __shared__ float p[64], z1[64], z2[16], z3[8];
  int g = blockIdx.x, f = threadIdx.x;
  float cv = fmaxf(cnt[g], 1.0f);
  p[f] = aP[f] * pooled[g * 64 + f] / cv + cP[f];
  __syncthreads();
  float a1 = m1b[f];
  for (int k = 0; k < 64; ++k) a1 += p[k] * m1w[k * 64 + f];
  z1[f] = fmaxf(a1, 0.f);
  __syncthreads();
  if (f < 16) {
    float a2 = m2b[f];
    for (int k = 0; k < 64; ++k) a2 += z1[k] * m2w[k * 16 + f];
    z2[f] = fmaxf(a2, 0.f);
  }
  __syncthreads();
  if (f < 8) {
    float a3 = m3b[f];
    for (int k = 0; k < 16; ++k) a3 += z2[k] * m3w[k * 8 + f];
    z3[f] = fmaxf(a3, 0.f);
  }
  __syncthreads();
  if (f < 10) {
    float a4 = m4b[f];
    for (int k = 0; k < 8; ++k) a4 += z3[k] * m4w[k * 10 + f];
    out[g * 10 + f] = a4;
  }
}

extern "C" void kernel_launch(void* const* d_in, const int* in_sizes, int n_in,
                              void* d_out, int out_size, void* d_ws, size_t ws_size,
                              hipStream_t stream) {
  const float* x   = (const float*)d_in[0];
  const int*   ei  = (const int*)d_in[1];
  const int*   bat = (const int*)d_in[2];
  const float* W1  = (const float*)d_in[3];
  const float* as1 = (const float*)d_in[4];
  const float* ad1 = (const float*)d_in[5];
  const float* b1  = (const float*)d_in[6];
  const float* W2  = (const float*)d_in[7];
  const float* as2 = (const float*)d_in[8];
  const float* ad2 = (const float*)d_in[9];
  const float* b2  = (const float*)d_in[10];
  const float* bng = (const float*)d_in[11];
  const float* bnb = (const float*)d_in[12];
  const float* m1w = (const float*)d_in[13];
  const float* m1b = (const float*)d_in[14];
  const float* m2w = (const float*)d_in[15];
  const float* m2b = (const float*)d_in[16];
  const float* m3w = (const float*)d_in[17];
  const float* m3b = (const float*)d_in[18];
  const float* m4w = (const float*)d_in[19];
  const float* m4b = (const float*)d_in[20];
  float* out = (float*)d_out;

  float* ws = (float*)d_ws;
  size_t off = 0;
  float* hbuf = ws + off; off += (size_t)NN * HID;   // GEMM output h (aliases stage)
  float* ybuf = ws + off; off += (size_t)NN * HID;   // layer output y
  float* sbuf = ws + off; off += NN;                 // alpha_s
  float* dbuf = ws + off; off += NN;                 // alpha_d
  int* deg    = (int*)(ws + off); off += NN;
  int* rowptr = (int*)(ws + off); off += NN + 1;
  int* cursor = (int*)(ws + off); off += NN;
  int* esrc   = (int*)(ws + off); off += ET;         // CSR: src per dst-sorted edge
  int* bsum   = (int*)(ws + off); off += SCAN_NB;
  int* bbase  = (int*)(ws + off); off += SCAN_NB;
  int* bcur   = (int*)(ws + off); off += NBUK;
  float* fsum = ws + off; off += HID;
  float* fsq  = ws + off; off += HID;
  float* aP   = ws + off; off += HID;                // BN scale
  float* cP   = ws + off; off += HID;                // BN shift
  float* pooled = ws + off; off += (size_t)NG * HID; // raw per-graph sums
  float* cnt  = ws + off; off += NG;
  int2* stage = (int2*)hbuf;  // 13.6MB staging aliases hbuf (free until gemm1)

  dim3 b256(256);
  const int gemmGrid = NN / 16;                      // 6250, exact
  const int edgeGrid = (ET + 255) / 256;
  const int p1Grid = (ET + P1_CHUNK - 1) / P1_CHUNK; // 416
  const int aggGrid = 2048;

  // ---------- CSR build (shared by both layers) ----------
  hipMemsetAsync(deg, 0, NN * 4, stream);
  hist_k<<<edgeGrid, b256, 0, stream>>>(ei, deg);
  scan_bsums_k<<<SCAN_NB, SCAN_T, 0, stream>>>(deg, bsum);
  scan_bbase_k<<<1, 64, 0, stream>>>(bsum, bbase);
  scan_final_k<<<SCAN_NB, SCAN_T, 0, stream>>>(deg, bbase, rowptr, cursor);
  bcur_init_k<<<1, 512, 0, stream>>>(rowptr, bcur, fsum, fsq);
  part1_k<<<p1Grid, b256, 0, stream>>>(ei, bcur, stage);
  part2_k<<<NBUK, b256, 0, stream>>>(stage, rowptr, cursor, esrc);

  // ---------- layer 1 ----------
  gemm_att<INF_><<<gemmGrid, b256, 0, stream>>>(x, nullptr, nullptr, W1, as1, ad1,
                                                hbuf, sbuf, dbuf);
  gat_agg_k<<<aggGrid, b256, 0, stream>>>(rowptr, esrc, sbuf, dbuf, hbuf, b1,
                                          ybuf, fsum, fsq);
  bn_params<<<1, 64, 0, stream>>>(fsum, fsq, bng, bnb, aP, cP, nullptr, nullptr);

  // ---------- layer 2 (BN affine folded into GEMM weight copy) ----------
  gemm_att<HID><<<gemmGrid, b256, 0, stream>>>(ybuf, aP, cP, W2, as2, ad2,
                                               hbuf, sbuf, dbuf);
  gat_agg_k<<<aggGrid, b256, 0, stream>>>(rowptr, esrc, sbuf, dbuf, hbuf, b2,
                                          ybuf, fsum, fsq);
  bn_params<<<1, 64, 0, stream>>>(fsum, fsq, bng, bnb, aP, cP, pooled, cnt);

  // ---------- pool (segmented, sorted batch) + MLP ----------
  pool_k<<<1024, b256, 0, stream>>>(ybuf, bat, pooled, cnt);
  mlp_head<<<NG, 64, 0, stream>>>(pooled, cnt, aP, cP, m1w, m1b, m2w, m2b,
                                  m3w, m3b, m4w, m4b, out);
}